// Round 2
// baseline (1254.317 us; speedup 1.0000x reference)
//
#include <hip/hip_runtime.h>
#include <math.h>

typedef short short8 __attribute__((ext_vector_type(8)));
typedef float floatx4 __attribute__((ext_vector_type(4)));

#define Bb 64
#define Ss 512
#define Hh 512
#define DFF 2048
#define HOPS 6
#define BS (Bb*Ss)          // 32768 positions
#define PS 1048576          // weight plane stride (elems), both w1f and w2f

// ---------------- fp32 -> 2x bf16 split (RNE via v_cvt_pk, exact residual) -
// q1 = {bf16(hi)<<16 | bf16(lo)}; residual limb = RNE(v - limb1_f): the
// split is self-correcting, total representation error ~2^-17 * |v|.
__device__ inline void split8_store2(const float* xs, unsigned short* dst,
                                     size_t psa) {
  unsigned q1[4], q2[4];
#pragma unroll
  for (int jj = 0; jj < 4; ++jj) {
    float lo = xs[2*jj], hi = xs[2*jj+1];
    unsigned p1;
    asm("v_cvt_pk_bf16_f32 %0, %1, %2" : "=v"(p1) : "v"(lo), "v"(hi));
    union { unsigned u; float f; } flo, fhi;
    flo.u = p1 << 16;
    fhi.u = p1 & 0xFFFF0000u;
    float rlo = lo - flo.f, rhi = hi - fhi.f;
    unsigned p2;
    asm("v_cvt_pk_bf16_f32 %0, %1, %2" : "=v"(p2) : "v"(rlo), "v"(rhi));
    q1[jj] = p1; q2[jj] = p2;
  }
  *(int4*)(dst)       = make_int4(q1[0], q1[1], q1[2], q1[3]);
  *(int4*)(dst + psa) = make_int4(q2[0], q2[1], q2[2], q2[3]);
}

// ---------------- async global->LDS 16B helper -----------------------------
__device__ __forceinline__ void gload16(const void* g, void* l) {
  __builtin_amdgcn_global_load_lds(
      (const __attribute__((address_space(1))) void*)g,
      (__attribute__((address_space(3))) void*)l, 16, 0, 0);
}

// ---------------- weight pre-split into fragment-linear planes -------------
__global__ __launch_bounds__(256) void prep_kernel(
    const float* __restrict__ w, unsigned short* __restrict__ wf,
    int K32, int NTOT, int N)
{
  int id = blockIdx.x * 256 + threadIdx.x;      // one per (k0,NT,lane)
  if (id >= K32 * NTOT * 64) return;
  int l  = id & 63;
  int NT = (id >> 6) % NTOT;
  int k0 = id / (64 * NTOT);
  int n  = NT * 16 + (l & 15);
  int kb = k0 * 32 + 8 * (l >> 4);
  float xs[8];
#pragma unroll
  for (int j = 0; j < 8; ++j) xs[j] = w[(size_t)(kb + j) * N + n];
  split8_store2(xs, wf + (size_t)id * 8, PS);
}

// ---------------- parallel compaction (order-free, outputs invariant) ------
__global__ __launch_bounds__(1024) void compact_kernel(
    const float* __restrict__ halting, int* __restrict__ idx,
    int* __restrict__ cnt)
{
  __shared__ int wsum[16];
  __shared__ int wbase[16];
  __shared__ int s_base;
  int tid = threadIdx.x;
  int lane = tid & 63, wid = tid >> 6;
  int pos = blockIdx.x * 1024 + tid;
  int flag = (halting[pos] < 1.0f) ? 1 : 0;
  unsigned long long m = __ballot(flag);
  int pre = __popcll(m & ((1ull << lane) - 1ull));
  if (lane == 0) wsum[wid] = __popcll(m);
  __syncthreads();
  if (tid == 0) {
    int a = 0;
#pragma unroll
    for (int i = 0; i < 16; ++i) { wbase[i] = a; a += wsum[i]; }
    s_base = (a > 0) ? atomicAdd(cnt, a) : 0;
  }
  __syncthreads();
  if (flag) idx[s_base + wbase[wid] + pre] = pos;
}

// ---------------- halting / p kernel (pure fp32) ---------------------------
__global__ __launch_bounds__(256) void halt_kernel(
    const float* __restrict__ st, const float* __restrict__ te,
    const float* __restrict__ pe_t, const float* __restrict__ wp,
    const float* __restrict__ bp, float* __restrict__ halting,
    float* __restrict__ remainders, float* __restrict__ n_updates,
    float* __restrict__ uw_c, const int* __restrict__ idxbuf,
    const int* __restrict__ cntp)
{
  int cnt = *cntp;
  int i = blockIdx.x * 4 + (threadIdx.x >> 6);
  if (i >= cnt) return;
  int lane = threadIdx.x & 63;
  int pos = idxbuf[i];
  int s = pos & (Ss - 1);
  const float4* stv = (const float4*)(st + (size_t)pos * Hh);
  const float4* tev = (const float4*)(te + (size_t)s * Hh);
  const float4* pev = (const float4*)pe_t;
  const float4* wpv = (const float4*)wp;
  float sum = 0.f;
#pragma unroll
  for (int j = 0; j < 2; ++j) {
    int idx = lane + j * 64;
    float4 a = stv[idx], b = tev[idx], c = pev[idx], w = wpv[idx];
    sum += (a.x + b.x + c.x) * w.x + (a.y + b.y + c.y) * w.y +
           (a.z + b.z + c.z) * w.z + (a.w + b.w + c.w) * w.w;
  }
#pragma unroll
  for (int off = 32; off > 0; off >>= 1) sum += __shfl_xor(sum, off, 64);
  if (lane == 0) {
    float y = sum + bp[0];
    float p = 1.0f / (1.0f + expf(-y));
    const float THRESH = 1.0f - 0.1f;
    float h0  = halting[pos];
    float rem = remainders[pos];
    float nup = n_updates[pos];
    float still = (h0 < 1.0f) ? 1.f : 0.f;
    float cand  = h0 + p * still;
    float nh  = ((cand >  THRESH) ? 1.f : 0.f) * still;
    float st2 = ((cand <= THRESH) ? 1.f : 0.f) * still;
    h0  += p * st2;
    rem += nh * (1.0f - h0);
    h0  += nh * rem;
    nup += st2 + nh;
    float uwv = p * st2 + nh * rem;
    halting[pos]    = h0;
    remainders[pos] = rem;
    n_updates[pos]  = nup;
    uw_c[i]         = uwv;
  }
}

// ---- stage_x: split x = st+te+pe (gathered) into bf16x2 fragment planes ---
__global__ __launch_bounds__(256) void stagex_kernel(
    const float* __restrict__ st, const float* __restrict__ te,
    const float* __restrict__ pe_t, unsigned short* __restrict__ xf,
    const int* __restrict__ idxbuf, const int* __restrict__ cntp,
    int m_base, int mrows, size_t psa)
{
  const int K32 = Hh / 32;
  int cnt = *cntp;
  int rel = cnt - m_base;
  if (rel <= 0) return;
  if (rel > mrows) rel = mrows;
  int rows_pad = (rel + 127) & ~127;
  if (rows_pad > mrows) rows_pad = mrows;
  int id = blockIdx.x * 256 + threadIdx.x;
  int l = id & 63;
  int f = id >> 6;
  int mtile = f / K32, k0 = f - mtile * K32;
  if (mtile * 16 >= rows_pad) return;
  int m = m_base + mtile * 16 + (l & 15);
  int mc = (m < cnt) ? m : cnt - 1;
  int pos = idxbuf[mc];
  int kb = k0 * 32 + (l >> 4) * 8;
  const float* ap = st + (size_t)pos * Hh + kb;
  const float* tp = te + (size_t)(pos & (Ss - 1)) * Hh + kb;
  const float* pp = pe_t + kb;
  float4 xa = *(const float4*)ap, xb = *(const float4*)(ap + 4);
  float4 ta = *(const float4*)tp, tb = *(const float4*)(tp + 4);
  float4 pa = *(const float4*)pp, pb = *(const float4*)(pp + 4);
  float xs[8];
  xs[0] = xa.x + ta.x + pa.x; xs[1] = xa.y + ta.y + pa.y;
  xs[2] = xa.z + ta.z + pa.z; xs[3] = xa.w + ta.w + pa.w;
  xs[4] = xb.x + tb.x + pb.x; xs[5] = xb.y + tb.y + pb.y;
  xs[6] = xb.z + tb.z + pb.z; xs[7] = xb.w + tb.w + pb.w;
  split8_store2(xs, xf + ((size_t)f * 64 + l) * 8, psa);
}

// ---- GEMM1 (LDS double-buffered, counted-vmcnt pipeline, 3-limb MFMA) -----
// block 128x128, 4 waves (2m x 2n), wave 64x64 = 4x4 frags of 16x16x32.
// Per k-step (32 k): stage A(16KB)+B(16KB) for the NEXT step via
// global_load_lds (8 issues/wave), s_waitcnt vmcnt(8) waits only the
// PREVIOUS stage -> loads stay in flight across barriers (T3-min + T4).
// setprio(1) around the MFMA cluster (T5): 2 independent blocks/CU give
// role diversity at barrier exits. XCD-chunked bijective blockIdx swizzle
// (T1/m204) so concurrent blocks per XCD share one xf strip working set.
// Epilogue repack LDS slice is PER-WAVE private -> no barriers needed there.
#define LSTR 66
__global__ __launch_bounds__(256, 2) void gemm1_kernel(
    const unsigned short* __restrict__ xf, const unsigned short* __restrict__ w1f,
    const float* __restrict__ b1, unsigned short* __restrict__ hf,
    const int* __restrict__ cntp, int m_base, size_t psa, size_t psh, int nst)
{
  __shared__ __align__(1024) char stage[65536];
  const int K32 = Hh / 32, NTOT = DFF / 16;
  int lin = blockIdx.x;
  // bijective XCD-chunk swizzle (nwg may not be %8==0 in general)
  int gsz = gridDim.x;
  int q = gsz >> 3, r = gsz & 7;
  int xcd = lin & 7, idx0 = lin >> 3;
  int swz = (xcd < r) ? (xcd * (q + 1) + idx0)
                      : (r * (q + 1) + (xcd - r) * q + idx0);
  int strip = swz >> 4;
  int nb    = swz & 15;
  int cnt = *cntp;
  int m0 = strip * 128;
  if (m_base + m0 >= cnt) return;
  int tid = threadIdx.x, lane = tid & 63, w = tid >> 6;
  int wm = w >> 1, wn = w & 1;
  int n0 = nb * 128;
  int mtb0 = m0 >> 4;
  int ntb0 = n0 >> 4;
  char* sptr = stage;

  // stage one 32-k fragment slab of A (2 limbs) + B (2 limbs) into buf bsel
  auto stage_step = [&](int bsel, int kk) {
    unsigned so = (unsigned)bsel * 32768u;
    int t0 = (w & 1) * 4;
    if (w < 2) {
#pragma unroll
      for (int j = 0; j < 4; ++j) {
        int mtile = t0 + j;
        const unsigned short* g0 =
            xf + ((size_t)(mtb0 + mtile) * K32 + kk) * 512 + (size_t)lane * 8;
        gload16(g0,       sptr + so + (unsigned)(mtile * 2 + 0) * 1024u);
        gload16(g0 + psa, sptr + so + (unsigned)(mtile * 2 + 1) * 1024u);
      }
    } else {
#pragma unroll
      for (int j = 0; j < 4; ++j) {
        int ntile = t0 + j;
        const unsigned short* g0 =
            w1f + ((size_t)kk * NTOT + (ntb0 + ntile)) * 512 + (size_t)lane * 8;
        gload16(g0,      sptr + so + 16384u + (unsigned)(ntile * 2 + 0) * 1024u);
        gload16(g0 + PS, sptr + so + 16384u + (unsigned)(ntile * 2 + 1) * 1024u);
      }
    }
  };

  floatx4 acc[4][4];
#pragma unroll
  for (int i = 0; i < 4; ++i)
#pragma unroll
    for (int j = 0; j < 4; ++j) acc[i][j] = (floatx4){0.f, 0.f, 0.f, 0.f};

  stage_step(0, 0);
  for (int k0 = 0; k0 < K32; ++k0) {
    int cur = k0 & 1;
    if (k0 + 1 < K32) {
      stage_step(cur ^ 1, k0 + 1);
      asm volatile("s_waitcnt vmcnt(8)" ::: "memory");   // prev stage landed
    } else {
      asm volatile("s_waitcnt vmcnt(0)" ::: "memory");
    }
    __builtin_amdgcn_s_barrier();                        // all waves staged
    asm volatile("" ::: "memory");
    const char* sb = sptr + cur * 32768 + (size_t)lane * 16;
    short8 af[2][4], bf[2][4];
#pragma unroll
    for (int mt = 0; mt < 4; ++mt) {
      af[0][mt] = *(const short8*)(sb + ((wm * 4 + mt) * 2 + 0) * 1024);
      af[1][mt] = *(const short8*)(sb + ((wm * 4 + mt) * 2 + 1) * 1024);
    }
#pragma unroll
    for (int nt = 0; nt < 4; ++nt) {
      bf[0][nt] = *(const short8*)(sb + 16384 + ((wn * 4 + nt) * 2 + 0) * 1024);
      bf[1][nt] = *(const short8*)(sb + 16384 + ((wn * 4 + nt) * 2 + 1) * 1024);
    }
    __builtin_amdgcn_s_setprio(1);
#pragma unroll
    for (int mt = 0; mt < 4; ++mt)
#pragma unroll
      for (int nt = 0; nt < 4; ++nt) {
        floatx4 c = acc[mt][nt];
        c = __builtin_amdgcn_mfma_f32_16x16x32_bf16(af[1][mt], bf[0][nt], c, 0, 0, 0);
        c = __builtin_amdgcn_mfma_f32_16x16x32_bf16(af[0][mt], bf[1][nt], c, 0, 0, 0);
        c = __builtin_amdgcn_mfma_f32_16x16x32_bf16(af[0][mt], bf[0][nt], c, 0, 0, 0);
        acc[mt][nt] = c;
      }
    __builtin_amdgcn_s_setprio(0);
    asm volatile("" ::: "memory");
    __builtin_amdgcn_s_barrier();  // all reads done before next overwrite
  }
  // epilogue: relu + bias; repack C-frag -> A-frag in 16-row slices.
  // L aliases the stage buffer (dead after the final barrier above) and is
  // PER-WAVE private: same-wave LDS write->read ordering is handled by the
  // compiler's lgkmcnt, no __syncthreads needed.
  {
    int r0 = (lane >> 4) * 4;       // C-layout row base within 16-row tile
    int c0l = lane & 15;            // C-layout col within 64-col wave tile
    int mtb = mtb0 + wm * 4;
    int k2b = (n0 >> 5) + wn * 2;
    float* L = (float*)(void*)sptr + (size_t)w * (16 * LSTR);
    float bias[4];
#pragma unroll
    for (int nt = 0; nt < 4; ++nt) bias[nt] = b1[n0 + wn * 64 + nt * 16 + c0l];
#pragma unroll
    for (int mt = 0; mt < 4; ++mt) {
#pragma unroll
      for (int nt = 0; nt < 4; ++nt)
#pragma unroll
        for (int reg = 0; reg < 4; ++reg)
          L[(r0 + reg) * LSTR + nt * 16 + c0l] =
              fmaxf(acc[mt][nt][reg] + bias[nt], 0.f);
#pragma unroll
      for (int k2 = 0; k2 < 2; ++k2) {
        const float* rp = L + (lane & 15) * LSTR + k2 * 32 + (lane >> 4) * 8;
        float xs[8];
        float4 xa = *(const float4*)rp, xb = *(const float4*)(rp + 4);
        xs[0]=xa.x; xs[1]=xa.y; xs[2]=xa.z; xs[3]=xa.w;
        xs[4]=xb.x; xs[5]=xb.y; xs[6]=xb.z; xs[7]=xb.w;
        size_t f2 = (size_t)(mtb + mt) * 64 + (k2b + k2);
        split8_store2(xs, hf + (f2 * 64 + lane) * 8, psh);
      }
    }
  }
}

// ---- GEMM2p (split-K partial writer, XCD-grouped): P[kp] = hf @ w2 --------
// BM=128 BN=128, 256 thr, 4 waves (2m x 2n), wave 64x64, 3-product limb.
// Same LDS double-buffered counted-vmcnt pipeline as gemm1, + setprio.
__global__ __launch_bounds__(256, 2) void gemm2p_kernel(
    const unsigned short* __restrict__ hf, const unsigned short* __restrict__ w2f,
    float* __restrict__ P, const int* __restrict__ cntp,
    int m_base, size_t psh, size_t pps, int nst)
{
  __shared__ __align__(1024) char stage[65536];
  const int K32 = DFF / 32, NTOT = Hh / 16, K32H = K32 / 2;
  int lin = blockIdx.x;
  int x   = lin & 7, sub = lin >> 3;
  int sk  = x + 8 * (sub >> 2);       // (strip,kp) index, grouped per XCD
  if (sk >= nst * 2) return;
  int strip = sk >> 1, kp = sk & 1, nb = sub & 3;
  int cnt = *cntp;
  int m0 = strip * 128;
  if (m_base + m0 >= cnt) return;
  int n0 = nb * 128;
  int tid = threadIdx.x, lane = tid & 63, w = tid >> 6;
  int wm = w >> 1, wn = w & 1;
  int mtb0 = m0 >> 4;
  int ntb0 = n0 >> 4;
  char* sptr = stage;

  auto stage_step = [&](int bsel, int kk) {
    unsigned so = (unsigned)bsel * 32768u;
    int t0 = (w & 1) * 4;
    if (w < 2) {
#pragma unroll
      for (int j = 0; j < 4; ++j) {
        int mtile = t0 + j;
        const unsigned short* g0 =
            hf + ((size_t)(mtb0 + mtile) * K32 + kk) * 512 + (size_t)lane * 8;
        gload16(g0,       sptr + so + (unsigned)(mtile * 2 + 0) * 1024u);
        gload16(g0 + psh, sptr + so + (unsigned)(mtile * 2 + 1) * 1024u);
      }
    } else {
#pragma unroll
      for (int j = 0; j < 4; ++j) {
        int ntile = t0 + j;
        const unsigned short* g0 =
            w2f + ((size_t)kk * NTOT + (ntb0 + ntile)) * 512 + (size_t)lane * 8;
        gload16(g0,      sptr + so + 16384u + (unsigned)(ntile * 2 + 0) * 1024u);
        gload16(g0 + PS, sptr + so + 16384u + (unsigned)(ntile * 2 + 1) * 1024u);
      }
    }
  };

  floatx4 acc[4][4];
#pragma unroll
  for (int i = 0; i < 4; ++i)
#pragma unroll
    for (int j = 0; j < 4; ++j) acc[i][j] = (floatx4){0.f, 0.f, 0.f, 0.f};

  int kbeg = kp * K32H, kend = kbeg + K32H;
  stage_step(0, kbeg);
  for (int k0 = kbeg; k0 < kend; ++k0) {
    int cur = (k0 - kbeg) & 1;
    if (k0 + 1 < kend) {
      stage_step(cur ^ 1, k0 + 1);
      asm volatile("s_waitcnt vmcnt(8)" ::: "memory");
    } else {
      asm volatile("s_waitcnt vmcnt(0)" ::: "memory");
    }
    __builtin_amdgcn_s_barrier();
    asm volatile("" ::: "memory");
    const char* sb = sptr + cur * 32768 + (size_t)lane * 16;
    short8 af[2][4], bf[2][4];
#pragma unroll
    for (int mt = 0; mt < 4; ++mt) {
      af[0][mt] = *(const short8*)(sb + ((wm * 4 + mt) * 2 + 0) * 1024);
      af[1][mt] = *(const short8*)(sb + ((wm * 4 + mt) * 2 + 1) * 1024);
    }
#pragma unroll
    for (int nt = 0; nt < 4; ++nt) {
      bf[0][nt] = *(const short8*)(sb + 16384 + ((wn * 4 + nt) * 2 + 0) * 1024);
      bf[1][nt] = *(const short8*)(sb + 16384 + ((wn * 4 + nt) * 2 + 1) * 1024);
    }
    __builtin_amdgcn_s_setprio(1);
#pragma unroll
    for (int mt = 0; mt < 4; ++mt)
#pragma unroll
      for (int nt = 0; nt < 4; ++nt) {
        floatx4 c = acc[mt][nt];
        c = __builtin_amdgcn_mfma_f32_16x16x32_bf16(af[1][mt], bf[0][nt], c, 0, 0, 0);
        c = __builtin_amdgcn_mfma_f32_16x16x32_bf16(af[0][mt], bf[1][nt], c, 0, 0, 0);
        c = __builtin_amdgcn_mfma_f32_16x16x32_bf16(af[0][mt], bf[0][nt], c, 0, 0, 0);
        acc[mt][nt] = c;
      }
    __builtin_amdgcn_s_setprio(0);
    asm volatile("" ::: "memory");
    __builtin_amdgcn_s_barrier();
  }
  float* Pb = P + (size_t)kp * pps;
  int mtb = mtb0 + wm * 4;
  int njb = ntb0 + wn * 4;
#pragma unroll
  for (int mt = 0; mt < 4; ++mt)
#pragma unroll
    for (int nt = 0; nt < 4; ++nt) {
      size_t f = (size_t)(mtb + mt) * 32 + (njb + nt);
      *(floatx4*)(Pb + (f * 64 + lane) * 4) = acc[mt][nt];
    }
}

// ---- reduce2: st = P0+P1+b2; prev = st*uw + prev*(1-uw) (scattered) -------
__global__ __launch_bounds__(256) void reduce2_kernel(
    const float* __restrict__ P, const float* __restrict__ b2,
    const float* __restrict__ uw_c, float* __restrict__ st_out,
    float* __restrict__ prev, const int* __restrict__ idxbuf,
    const int* __restrict__ cntp, int m_base, size_t pps)
{
  int cnt = *cntp;
  int id = blockIdx.x * 256 + threadIdx.x;
  int lane = id & 63;
  int f = id >> 6;
  int mi = f >> 5, nj = f & 31;
  if (m_base + mi * 16 >= cnt) return;
  floatx4 p0 = *(const floatx4*)(P + ((size_t)f * 64 + lane) * 4);
  floatx4 p1 = *(const floatx4*)(P + pps + ((size_t)f * 64 + lane) * 4);
  int col = nj * 16 + (lane & 15);
  float bias = b2[col];
  int r0 = (lane >> 4) * 4;
#pragma unroll
  for (int reg = 0; reg < 4; ++reg) {
    int m = m_base + mi * 16 + r0 + reg;
    if (m < cnt) {
      int pos = idxbuf[m];
      float uwv = uw_c[m];
      float sv = p0[reg] + p1[reg] + bias;
      size_t off = (size_t)pos * Hh + col;
      float pv = prev[off];
      st_out[off] = sv;
      prev[off] = sv * uwv + pv * (1.f - uwv);
    }
  }
}

extern "C" void kernel_launch(void* const* d_in, const int* in_sizes, int n_in,
                              void* d_out, int out_size, void* d_ws, size_t ws_size,
                              hipStream_t stream) {
  const float* state  = (const float*)d_in[0];
  const float* te     = (const float*)d_in[2];
  const float* pe     = (const float*)d_in[3];
  const float* wp     = (const float*)d_in[4];
  const float* bp     = (const float*)d_in[5];
  const float* w1     = (const float*)d_in[6];
  const float* b1     = (const float*)d_in[7];
  const float* w2     = (const float*)d_in[8];
  const float* b2     = (const float*)d_in[9];

  float* out        = (float*)d_out;
  float* prev       = out;                          // BS*H
  float* remainders = out + (size_t)BS * Hh;        // BS
  float* n_updates  = remainders + BS;              // BS

  float*          st      = (float*)d_ws;           // BS*H (67 MB)
  float*          halting = st + (size_t)BS * Hh;   // BS
  float*          uw_c    = halting + BS;           // BS
  int*            idxbuf  = (int*)(uw_c + BS);      // BS
  int*            cntp    = idxbuf + BS;            // 64 (one counter per hop)
  unsigned short* w1f     = (unsigned short*)(cntp + 64);   // 2*PS (4 MB)
  unsigned short* w2f     = w1f + 2 * (size_t)PS;           // 2*PS (4 MB)
  unsigned short* hf      = w2f + 2 * (size_t)PS;

  size_t fixed = (size_t)((char*)hf - (char*)d_ws);
  size_t avail = (ws_size > fixed) ? (ws_size - fixed) : 0;
  // per row: hf = 2*2048*2 = 8192 B ; C = max(xf 2048 B, P 4096 B) = 4096 B
  int hrows = (int)((avail / 12288) & ~(size_t)127);
  if (hrows > BS) hrows = BS;
  if (hrows < 128) hrows = 128;
  // C region (xf and P alias each other: xf dead after gemm1, P born after)
  char* Cbase = (char*)hf + (size_t)hrows * DFF * 2 * 2;
  unsigned short* xf = (unsigned short*)Cbase;
  float*          Pb = (float*)Cbase;
  size_t psa = (size_t)hrows * Hh;    // xf plane stride (ushort elems)
  size_t psh = (size_t)hrows * DFF;   // hf plane stride (ushort elems)
  size_t pps = (size_t)hrows * Hh;    // P plane stride (floats)
  int nst = hrows / 128;

  hipMemsetAsync(d_out, 0, (size_t)out_size * sizeof(float), stream);
  hipMemsetAsync(halting, 0, (size_t)BS * sizeof(float), stream);
  hipMemsetAsync(cntp, 0, 64 * sizeof(int), stream);
  hipMemcpyAsync(st, state, (size_t)BS * Hh * sizeof(float),
                 hipMemcpyDeviceToDevice, stream);

  prep_kernel<<<512, 256, 0, stream>>>(w1, w1f, Hh / 32, DFF / 16, DFF);
  prep_kernel<<<512, 256, 0, stream>>>(w2, w2f, DFF / 32, Hh / 16, Hh);

  int g2grid = (((nst * 2 + 7) & ~7)) * 4;
  for (int t = 0; t < HOPS; ++t) {
    const float* pe_t = pe + (size_t)t * Hh;
    int* cnt_t = cntp + t;
    compact_kernel<<<BS / 1024, 1024, 0, stream>>>(halting, idxbuf, cnt_t);
    halt_kernel<<<BS / 4, 256, 0, stream>>>(st, te, pe_t, wp, bp, halting,
                                            remainders, n_updates, uw_c,
                                            idxbuf, cnt_t);
    for (int mb = 0; mb < BS; mb += hrows) {
      stagex_kernel<<<hrows / 4, 256, 0, stream>>>(st, te, pe_t, xf, idxbuf,
                                                   cnt_t, mb, hrows, psa);
      gemm1_kernel<<<nst * 16, 256, 0, stream>>>(xf, w1f, b1, hf, cnt_t, mb,
                                                 psa, psh, nst);
      gemm2p_kernel<<<g2grid, 256, 0, stream>>>(hf, w2f, Pb, cnt_t, mb,
                                                psh, pps, nst);
      reduce2_kernel<<<hrows / 2, 256, 0, stream>>>(Pb, b2, uw_c, st, prev,
                                                    idxbuf, cnt_t, mb, pps);
    }
  }
}

// Round 3
// 1044.658 us; speedup vs baseline: 1.2007x; 1.2007x over previous
//
#include <hip/hip_runtime.h>
#include <math.h>

typedef short short8 __attribute__((ext_vector_type(8)));
typedef float floatx4 __attribute__((ext_vector_type(4)));

#define Bb 64
#define Ss 512
#define Hh 512
#define DFF 2048
#define HOPS 6
#define BS (Bb*Ss)          // 32768 positions
#define PS 1048576          // weight plane stride (elems), both w1f and w2f

// ---------------- fp32 -> 2x bf16 split (RNE, exact residual) --------------
// Manual bit-twiddle RNE (R1-proven). m240: hand-written v_cvt_pk inline asm
// is SLOWER than compiler-scheduled plain ops -- do not reintroduce.
__device__ inline unsigned bf16rne(float v) {
  union { float f; unsigned u; } a; a.f = v;
  return (a.u + 0x7fffu + ((a.u >> 16) & 1u)) >> 16;
}
__device__ inline void split2(float v, unsigned &h1, unsigned &h2) {
  h1 = bf16rne(v);
  union { unsigned u; float f; } b1; b1.u = h1 << 16;
  h2 = bf16rne(v - b1.f);
}
__device__ inline void split8_store2(const float* xs, unsigned short* dst,
                                     size_t psa) {
  unsigned q1[4], q2[4];
#pragma unroll
  for (int jj = 0; jj < 4; ++jj) {
    unsigned a1, a2, c1, c2;
    split2(xs[2*jj],   a1, a2);
    split2(xs[2*jj+1], c1, c2);
    q1[jj] = a1 | (c1 << 16);
    q2[jj] = a2 | (c2 << 16);
  }
  *(int4*)(dst)       = make_int4(q1[0], q1[1], q1[2], q1[3]);
  *(int4*)(dst + psa) = make_int4(q2[0], q2[1], q2[2], q2[3]);
}

// ---------------- async global->LDS 16B helper -----------------------------
__device__ __forceinline__ void gload16(const void* g, void* l) {
  __builtin_amdgcn_global_load_lds(
      (const __attribute__((address_space(1))) void*)g,
      (__attribute__((address_space(3))) void*)l, 16, 0, 0);
}

// ---------------- weight pre-split into fragment-linear planes -------------
__global__ __launch_bounds__(256) void prep_kernel(
    const float* __restrict__ w, unsigned short* __restrict__ wf,
    int K32, int NTOT, int N)
{
  int id = blockIdx.x * 256 + threadIdx.x;      // one per (k0,NT,lane)
  if (id >= K32 * NTOT * 64) return;
  int l  = id & 63;
  int NT = (id >> 6) % NTOT;
  int k0 = id / (64 * NTOT);
  int n  = NT * 16 + (l & 15);
  int kb = k0 * 32 + 8 * (l >> 4);
  float xs[8];
#pragma unroll
  for (int j = 0; j < 8; ++j) xs[j] = w[(size_t)(kb + j) * N + n];
  split8_store2(xs, wf + (size_t)id * 8, PS);
}

// ---------------- parallel compaction (order-free, outputs invariant) ------
__global__ __launch_bounds__(1024) void compact_kernel(
    const float* __restrict__ halting, int* __restrict__ idx,
    int* __restrict__ cnt)
{
  __shared__ int wsum[16];
  __shared__ int wbase[16];
  __shared__ int s_base;
  int tid = threadIdx.x;
  int lane = tid & 63, wid = tid >> 6;
  int pos = blockIdx.x * 1024 + tid;
  int flag = (halting[pos] < 1.0f) ? 1 : 0;
  unsigned long long m = __ballot(flag);
  int pre = __popcll(m & ((1ull << lane) - 1ull));
  if (lane == 0) wsum[wid] = __popcll(m);
  __syncthreads();
  if (tid == 0) {
    int a = 0;
#pragma unroll
    for (int i = 0; i < 16; ++i) { wbase[i] = a; a += wsum[i]; }
    s_base = (a > 0) ? atomicAdd(cnt, a) : 0;
  }
  __syncthreads();
  if (flag) idx[s_base + wbase[wid] + pre] = pos;
}

// ---------------- halting / p kernel (pure fp32) ---------------------------
__global__ __launch_bounds__(256) void halt_kernel(
    const float* __restrict__ st, const float* __restrict__ te,
    const float* __restrict__ pe_t, const float* __restrict__ wp,
    const float* __restrict__ bp, float* __restrict__ halting,
    float* __restrict__ remainders, float* __restrict__ n_updates,
    float* __restrict__ uw_c, const int* __restrict__ idxbuf,
    const int* __restrict__ cntp)
{
  int cnt = *cntp;
  int i = blockIdx.x * 4 + (threadIdx.x >> 6);
  if (i >= cnt) return;
  int lane = threadIdx.x & 63;
  int pos = idxbuf[i];
  int s = pos & (Ss - 1);
  const float4* stv = (const float4*)(st + (size_t)pos * Hh);
  const float4* tev = (const float4*)(te + (size_t)s * Hh);
  const float4* pev = (const float4*)pe_t;
  const float4* wpv = (const float4*)wp;
  float sum = 0.f;
#pragma unroll
  for (int j = 0; j < 2; ++j) {
    int idx = lane + j * 64;
    float4 a = stv[idx], b = tev[idx], c = pev[idx], w = wpv[idx];
    sum += (a.x + b.x + c.x) * w.x + (a.y + b.y + c.y) * w.y +
           (a.z + b.z + c.z) * w.z + (a.w + b.w + c.w) * w.w;
  }
#pragma unroll
  for (int off = 32; off > 0; off >>= 1) sum += __shfl_xor(sum, off, 64);
  if (lane == 0) {
    float y = sum + bp[0];
    float p = 1.0f / (1.0f + expf(-y));
    const float THRESH = 1.0f - 0.1f;
    float h0  = halting[pos];
    float rem = remainders[pos];
    float nup = n_updates[pos];
    float still = (h0 < 1.0f) ? 1.f : 0.f;
    float cand  = h0 + p * still;
    float nh  = ((cand >  THRESH) ? 1.f : 0.f) * still;
    float st2 = ((cand <= THRESH) ? 1.f : 0.f) * still;
    h0  += p * st2;
    rem += nh * (1.0f - h0);
    h0  += nh * rem;
    nup += st2 + nh;
    float uwv = p * st2 + nh * rem;
    halting[pos]    = h0;
    remainders[pos] = rem;
    n_updates[pos]  = nup;
    uw_c[i]         = uwv;
  }
}

// ---- stage_x: split x = st+te+pe (gathered) into bf16x2 fragment planes ---
__global__ __launch_bounds__(256) void stagex_kernel(
    const float* __restrict__ st, const float* __restrict__ te,
    const float* __restrict__ pe_t, unsigned short* __restrict__ xf,
    const int* __restrict__ idxbuf, const int* __restrict__ cntp,
    int m_base, int mrows, size_t psa)
{
  const int K32 = Hh / 32;
  int cnt = *cntp;
  int rel = cnt - m_base;
  if (rel <= 0) return;
  if (rel > mrows) rel = mrows;
  int rows_pad = (rel + 127) & ~127;
  if (rows_pad > mrows) rows_pad = mrows;
  int id = blockIdx.x * 256 + threadIdx.x;
  int l = id & 63;
  int f = id >> 6;
  int mtile = f / K32, k0 = f - mtile * K32;
  if (mtile * 16 >= rows_pad) return;
  int m = m_base + mtile * 16 + (l & 15);
  int mc = (m < cnt) ? m : cnt - 1;
  int pos = idxbuf[mc];
  int kb = k0 * 32 + (l >> 4) * 8;
  const float* ap = st + (size_t)pos * Hh + kb;
  const float* tp = te + (size_t)(pos & (Ss - 1)) * Hh + kb;
  const float* pp = pe_t + kb;
  float4 xa = *(const float4*)ap, xb = *(const float4*)(ap + 4);
  float4 ta = *(const float4*)tp, tb = *(const float4*)(tp + 4);
  float4 pa = *(const float4*)pp, pb = *(const float4*)(pp + 4);
  float xs[8];
  xs[0] = xa.x + ta.x + pa.x; xs[1] = xa.y + ta.y + pa.y;
  xs[2] = xa.z + ta.z + pa.z; xs[3] = xa.w + ta.w + pa.w;
  xs[4] = xb.x + tb.x + pb.x; xs[5] = xb.y + tb.y + pb.y;
  xs[6] = xb.z + tb.z + pb.z; xs[7] = xb.w + tb.w + pb.w;
  split8_store2(xs, xf + ((size_t)f * 64 + l) * 8, psa);
}

// ---- GEMM1 (LDS double-buffered, counted-vmcnt pipeline, 3-limb MFMA) -----
// block 128x128, 4 waves (2m x 2n), wave 64x64 = 4x4 frags of 16x16x32.
// Per k-step: stage next A(16KB)+B(16KB) via global_load_lds (8/wave),
// s_waitcnt vmcnt(8) waits only the PREVIOUS stage (T3-min + T4).
// setprio around MFMA (kept: part of measured-fastest R2 config).
// Bijective XCD-chunk swizzle (T1/m204). Epilogue LDS slice is per-wave
// private -> no barriers there.
#define LSTR 66
__global__ __launch_bounds__(256, 2) void gemm1_kernel(
    const unsigned short* __restrict__ xf, const unsigned short* __restrict__ w1f,
    const float* __restrict__ b1, unsigned short* __restrict__ hf,
    const int* __restrict__ cntp, int m_base, size_t psa, size_t psh, int nst)
{
  __shared__ __align__(1024) char stage[65536];
  const int K32 = Hh / 32, NTOT = DFF / 16;
  int lin = blockIdx.x;
  int gsz = gridDim.x;
  int q = gsz >> 3, r = gsz & 7;
  int xcd = lin & 7, idx0 = lin >> 3;
  int swz = (xcd < r) ? (xcd * (q + 1) + idx0)
                      : (r * (q + 1) + (xcd - r) * q + idx0);
  int strip = swz >> 4;
  int nb    = swz & 15;
  int cnt = *cntp;
  int m0 = strip * 128;
  if (m_base + m0 >= cnt) return;
  int tid = threadIdx.x, lane = tid & 63, w = tid >> 6;
  int wm = w >> 1, wn = w & 1;
  int n0 = nb * 128;
  int mtb0 = m0 >> 4;
  int ntb0 = n0 >> 4;
  char* sptr = stage;

  auto stage_step = [&](int bsel, int kk) {
    unsigned so = (unsigned)bsel * 32768u;
    int t0 = (w & 1) * 4;
    if (w < 2) {
#pragma unroll
      for (int j = 0; j < 4; ++j) {
        int mtile = t0 + j;
        const unsigned short* g0 =
            xf + ((size_t)(mtb0 + mtile) * K32 + kk) * 512 + (size_t)lane * 8;
        gload16(g0,       sptr + so + (unsigned)(mtile * 2 + 0) * 1024u);
        gload16(g0 + psa, sptr + so + (unsigned)(mtile * 2 + 1) * 1024u);
      }
    } else {
#pragma unroll
      for (int j = 0; j < 4; ++j) {
        int ntile = t0 + j;
        const unsigned short* g0 =
            w1f + ((size_t)kk * NTOT + (ntb0 + ntile)) * 512 + (size_t)lane * 8;
        gload16(g0,      sptr + so + 16384u + (unsigned)(ntile * 2 + 0) * 1024u);
        gload16(g0 + PS, sptr + so + 16384u + (unsigned)(ntile * 2 + 1) * 1024u);
      }
    }
  };

  floatx4 acc[4][4];
#pragma unroll
  for (int i = 0; i < 4; ++i)
#pragma unroll
    for (int j = 0; j < 4; ++j) acc[i][j] = (floatx4){0.f, 0.f, 0.f, 0.f};

  stage_step(0, 0);
  for (int k0 = 0; k0 < K32; ++k0) {
    int cur = k0 & 1;
    if (k0 + 1 < K32) {
      stage_step(cur ^ 1, k0 + 1);
      asm volatile("s_waitcnt vmcnt(8)" ::: "memory");   // prev stage landed
    } else {
      asm volatile("s_waitcnt vmcnt(0)" ::: "memory");
    }
    __builtin_amdgcn_s_barrier();                        // all waves staged
    asm volatile("" ::: "memory");
    const char* sb = sptr + cur * 32768 + (size_t)lane * 16;
    short8 af[2][4], bf[2][4];
#pragma unroll
    for (int mt = 0; mt < 4; ++mt) {
      af[0][mt] = *(const short8*)(sb + ((wm * 4 + mt) * 2 + 0) * 1024);
      af[1][mt] = *(const short8*)(sb + ((wm * 4 + mt) * 2 + 1) * 1024);
    }
#pragma unroll
    for (int nt = 0; nt < 4; ++nt) {
      bf[0][nt] = *(const short8*)(sb + 16384 + ((wn * 4 + nt) * 2 + 0) * 1024);
      bf[1][nt] = *(const short8*)(sb + 16384 + ((wn * 4 + nt) * 2 + 1) * 1024);
    }
    __builtin_amdgcn_s_setprio(1);
#pragma unroll
    for (int mt = 0; mt < 4; ++mt)
#pragma unroll
      for (int nt = 0; nt < 4; ++nt) {
        floatx4 c = acc[mt][nt];
        c = __builtin_amdgcn_mfma_f32_16x16x32_bf16(af[1][mt], bf[0][nt], c, 0, 0, 0);
        c = __builtin_amdgcn_mfma_f32_16x16x32_bf16(af[0][mt], bf[1][nt], c, 0, 0, 0);
        c = __builtin_amdgcn_mfma_f32_16x16x32_bf16(af[0][mt], bf[0][nt], c, 0, 0, 0);
        acc[mt][nt] = c;
      }
    __builtin_amdgcn_s_setprio(0);
    asm volatile("" ::: "memory");
    __builtin_amdgcn_s_barrier();  // all reads done before next overwrite
  }
  // epilogue: relu + bias; repack C-frag -> A-frag in 16-row slices.
  // Per-wave private LDS slice (aliases dead stage buffer), no barriers.
  {
    int r0 = (lane >> 4) * 4;
    int c0l = lane & 15;
    int mtb = mtb0 + wm * 4;
    int k2b = (n0 >> 5) + wn * 2;
    float* L = (float*)(void*)sptr + (size_t)w * (16 * LSTR);
    float bias[4];
#pragma unroll
    for (int nt = 0; nt < 4; ++nt) bias[nt] = b1[n0 + wn * 64 + nt * 16 + c0l];
#pragma unroll
    for (int mt = 0; mt < 4; ++mt) {
#pragma unroll
      for (int nt = 0; nt < 4; ++nt)
#pragma unroll
        for (int reg = 0; reg < 4; ++reg)
          L[(r0 + reg) * LSTR + nt * 16 + c0l] =
              fmaxf(acc[mt][nt][reg] + bias[nt], 0.f);
#pragma unroll
      for (int k2 = 0; k2 < 2; ++k2) {
        const float* rp = L + (lane & 15) * LSTR + k2 * 32 + (lane >> 4) * 8;
        float xs[8];
        float4 xa = *(const float4*)rp, xb = *(const float4*)(rp + 4);
        xs[0]=xa.x; xs[1]=xa.y; xs[2]=xa.z; xs[3]=xa.w;
        xs[4]=xb.x; xs[5]=xb.y; xs[6]=xb.z; xs[7]=xb.w;
        size_t f2 = (size_t)(mtb + mt) * 64 + (k2b + k2);
        split8_store2(xs, hf + (f2 * 64 + lane) * 8, psh);
      }
    }
  }
}

// ---- GEMM2f (FULL-K, fused bias + uw-blend scatter epilogue) --------------
// Replaces gemm2p (split-K) + reduce2: kills the P round-trip (134 MB/chunk).
// grid = nst*4 blocks (>= 2/CU at hrows=16384). Same LDS double-buffered
// counted-vmcnt pipeline. No setprio (m190: hurts lockstep GEMM).
__global__ __launch_bounds__(256, 2) void gemm2f_kernel(
    const unsigned short* __restrict__ hf, const unsigned short* __restrict__ w2f,
    const float* __restrict__ b2, const float* __restrict__ uw_c,
    float* __restrict__ st_out, float* __restrict__ prev,
    const int* __restrict__ idxbuf, const int* __restrict__ cntp,
    int m_base, size_t psh, int nst)
{
  __shared__ __align__(1024) char stage[65536];
  const int K32 = DFF / 32, NTOT = Hh / 16;
  int lin = blockIdx.x;
  int gsz = gridDim.x;
  int q = gsz >> 3, r = gsz & 7;
  int xcd = lin & 7, idx0 = lin >> 3;
  int swz = (xcd < r) ? (xcd * (q + 1) + idx0)
                      : (r * (q + 1) + (xcd - r) * q + idx0);
  int strip = swz >> 2, nb = swz & 3;
  int cnt = *cntp;
  int m0 = strip * 128;
  if (m_base + m0 >= cnt) return;
  int n0 = nb * 128;
  int tid = threadIdx.x, lane = tid & 63, w = tid >> 6;
  int wm = w >> 1, wn = w & 1;
  int mtb0 = m0 >> 4;
  int ntb0 = n0 >> 4;
  char* sptr = stage;

  auto stage_step = [&](int bsel, int kk) {
    unsigned so = (unsigned)bsel * 32768u;
    int t0 = (w & 1) * 4;
    if (w < 2) {
#pragma unroll
      for (int j = 0; j < 4; ++j) {
        int mtile = t0 + j;
        const unsigned short* g0 =
            hf + ((size_t)(mtb0 + mtile) * K32 + kk) * 512 + (size_t)lane * 8;
        gload16(g0,       sptr + so + (unsigned)(mtile * 2 + 0) * 1024u);
        gload16(g0 + psh, sptr + so + (unsigned)(mtile * 2 + 1) * 1024u);
      }
    } else {
#pragma unroll
      for (int j = 0; j < 4; ++j) {
        int ntile = t0 + j;
        const unsigned short* g0 =
            w2f + ((size_t)kk * NTOT + (ntb0 + ntile)) * 512 + (size_t)lane * 8;
        gload16(g0,      sptr + so + 16384u + (unsigned)(ntile * 2 + 0) * 1024u);
        gload16(g0 + PS, sptr + so + 16384u + (unsigned)(ntile * 2 + 1) * 1024u);
      }
    }
  };

  floatx4 acc[4][4];
#pragma unroll
  for (int i = 0; i < 4; ++i)
#pragma unroll
    for (int j = 0; j < 4; ++j) acc[i][j] = (floatx4){0.f, 0.f, 0.f, 0.f};

  stage_step(0, 0);
  for (int k0 = 0; k0 < K32; ++k0) {
    int cur = k0 & 1;
    if (k0 + 1 < K32) {
      stage_step(cur ^ 1, k0 + 1);
      asm volatile("s_waitcnt vmcnt(8)" ::: "memory");
    } else {
      asm volatile("s_waitcnt vmcnt(0)" ::: "memory");
    }
    __builtin_amdgcn_s_barrier();
    asm volatile("" ::: "memory");
    const char* sb = sptr + cur * 32768 + (size_t)lane * 16;
    short8 af[2][4], bf[2][4];
#pragma unroll
    for (int mt = 0; mt < 4; ++mt) {
      af[0][mt] = *(const short8*)(sb + ((wm * 4 + mt) * 2 + 0) * 1024);
      af[1][mt] = *(const short8*)(sb + ((wm * 4 + mt) * 2 + 1) * 1024);
    }
#pragma unroll
    for (int nt = 0; nt < 4; ++nt) {
      bf[0][nt] = *(const short8*)(sb + 16384 + ((wn * 4 + nt) * 2 + 0) * 1024);
      bf[1][nt] = *(const short8*)(sb + 16384 + ((wn * 4 + nt) * 2 + 1) * 1024);
    }
#pragma unroll
    for (int mt = 0; mt < 4; ++mt)
#pragma unroll
      for (int nt = 0; nt < 4; ++nt) {
        floatx4 c = acc[mt][nt];
        c = __builtin_amdgcn_mfma_f32_16x16x32_bf16(af[1][mt], bf[0][nt], c, 0, 0, 0);
        c = __builtin_amdgcn_mfma_f32_16x16x32_bf16(af[0][mt], bf[1][nt], c, 0, 0, 0);
        c = __builtin_amdgcn_mfma_f32_16x16x32_bf16(af[0][mt], bf[0][nt], c, 0, 0, 0);
        acc[mt][nt] = c;
      }
    asm volatile("" ::: "memory");
    __builtin_amdgcn_s_barrier();
  }
  // fused epilogue: sv = acc + b2; st_out = sv; prev = sv*uw + prev*(1-uw)
  // C layout: row = (mtb0+wm*4+mt)*16 + (lane>>4)*4 + reg (chunk-relative),
  //           col = (ntb0+wn*4+nt)*16 + (lane&15).
  {
    int r0 = (lane >> 4) * 4;
    int c0l = lane & 15;
    int mtb = mtb0 + wm * 4;
    int njb = ntb0 + wn * 4;
    float bias[4];
#pragma unroll
    for (int nt = 0; nt < 4; ++nt) bias[nt] = b2[(njb + nt) * 16 + c0l];
#pragma unroll
    for (int mt = 0; mt < 4; ++mt) {
      int pos4[4]; float uw4[4]; bool ok4[4];
#pragma unroll
      for (int reg = 0; reg < 4; ++reg) {
        int m = m_base + (mtb + mt) * 16 + r0 + reg;
        ok4[reg] = (m < cnt);
        int mc = ok4[reg] ? m : 0;
        pos4[reg] = idxbuf[mc];
        uw4[reg]  = uw_c[mc];
      }
#pragma unroll
      for (int nt = 0; nt < 4; ++nt) {
        int col = (njb + nt) * 16 + c0l;
#pragma unroll
        for (int reg = 0; reg < 4; ++reg) {
          if (ok4[reg]) {
            float sv = acc[mt][nt][reg] + bias[nt];
            size_t off = (size_t)pos4[reg] * Hh + col;
            float pv = prev[off];
            st_out[off] = sv;
            prev[off] = sv * uw4[reg] + pv * (1.f - uw4[reg]);
          }
        }
      }
    }
  }
}

extern "C" void kernel_launch(void* const* d_in, const int* in_sizes, int n_in,
                              void* d_out, int out_size, void* d_ws, size_t ws_size,
                              hipStream_t stream) {
  const float* state  = (const float*)d_in[0];
  const float* te     = (const float*)d_in[2];
  const float* pe     = (const float*)d_in[3];
  const float* wp     = (const float*)d_in[4];
  const float* bp     = (const float*)d_in[5];
  const float* w1     = (const float*)d_in[6];
  const float* b1     = (const float*)d_in[7];
  const float* w2     = (const float*)d_in[8];
  const float* b2     = (const float*)d_in[9];

  float* out        = (float*)d_out;
  float* prev       = out;                          // BS*H
  float* remainders = out + (size_t)BS * Hh;        // BS
  float* n_updates  = remainders + BS;              // BS

  float*          st      = (float*)d_ws;           // BS*H (67 MB)
  float*          halting = st + (size_t)BS * Hh;   // BS
  float*          uw_c    = halting + BS;           // BS
  int*            idxbuf  = (int*)(uw_c + BS);      // BS
  int*            cntp    = idxbuf + BS;            // 64 (one counter per hop)
  unsigned short* w1f     = (unsigned short*)(cntp + 64);   // 2*PS (4 MB)
  unsigned short* w2f     = w1f + 2 * (size_t)PS;           // 2*PS (4 MB)
  unsigned short* hf      = w2f + 2 * (size_t)PS;

  size_t fixed = (size_t)((char*)hf - (char*)d_ws);
  size_t avail = (ws_size > fixed) ? (ws_size - fixed) : 0;
  // per row: hf = 2*2048*2 = 8192 B ; xf = 2048 B
  int hrows = (int)((avail / 10240) & ~(size_t)127);
  if (hrows > 16384) hrows = 16384;  // keep hf chunk L3-resident
  if (hrows < 128) hrows = 128;
  unsigned short* xf = (unsigned short*)((char*)hf + (size_t)hrows * DFF * 2 * 2);
  size_t psa = (size_t)hrows * Hh;    // xf plane stride (ushort elems)
  size_t psh = (size_t)hrows * DFF;   // hf plane stride (ushort elems)
  int nst = hrows / 128;

  hipMemsetAsync(d_out, 0, (size_t)out_size * sizeof(float), stream);
  hipMemsetAsync(halting, 0, (size_t)BS * sizeof(float), stream);
  hipMemsetAsync(cntp, 0, 64 * sizeof(int), stream);
  hipMemcpyAsync(st, state, (size_t)BS * Hh * sizeof(float),
                 hipMemcpyDeviceToDevice, stream);

  prep_kernel<<<512, 256, 0, stream>>>(w1, w1f, Hh / 32, DFF / 16, DFF);
  prep_kernel<<<512, 256, 0, stream>>>(w2, w2f, DFF / 32, Hh / 16, Hh);

  for (int t = 0; t < HOPS; ++t) {
    const float* pe_t = pe + (size_t)t * Hh;
    int* cnt_t = cntp + t;
    compact_kernel<<<BS / 1024, 1024, 0, stream>>>(halting, idxbuf, cnt_t);
    halt_kernel<<<BS / 4, 256, 0, stream>>>(st, te, pe_t, wp, bp, halting,
                                            remainders, n_updates, uw_c,
                                            idxbuf, cnt_t);
    for (int mb = 0; mb < BS; mb += hrows) {
      stagex_kernel<<<hrows / 4, 256, 0, stream>>>(st, te, pe_t, xf, idxbuf,
                                                   cnt_t, mb, hrows, psa);
      gemm1_kernel<<<nst * 16, 256, 0, stream>>>(xf, w1f, b1, hf, cnt_t, mb,
                                                 psa, psh, nst);
      gemm2f_kernel<<<nst * 4, 256, 0, stream>>>(hf, w2f, b2, uw_c, st, prev,
                                                 idxbuf, cnt_t, mb, psh, nst);
    }
  }
}